// Round 15
// baseline (283.344 us; speedup 1.0000x reference)
//
#include <hip/hip_runtime.h>
#include <math.h>

// ---- problem constants (fixed shapes) ----
#define NPTS 16384
#define DIM  512
#define KSEL 11                   // K+1 smallest incl. self; min dropped at the end
#define NSPLIT 8
#define CPS   (NPTS / NSPLIT)     // 2048 columns per split (main)
#define BMM   256                 // knn_main rows per block (4 waves x 64 rows)
#define BMT   128                 // thresh rows per block (4 waves x 32 rows)
#define BN    64                  // columns staged per iteration (32 KB in i8)
#define MITERS (CPS / BN)         // 32 main iterations per split
#define TITERS 16                 // threshold pass: 1024 cols per quarter-sample
#define TCH   4096                // thresh quarter stride
#define STRIPB 16384              // bytes per 32-row/col fragment-major strip (i8)
#define CAP   24                  // appended candidates per (row, split)
#define QS    22.0f               // quantization scale: x_i8 = clamp(rint(22 x), +-127)

typedef __attribute__((ext_vector_type(4)))  int i32x4;
typedef __attribute__((ext_vector_type(16))) int i32x16;

__device__ __forceinline__ void gload_lds16(const void* g, void* l) {
    __builtin_amdgcn_global_load_lds(
        (const __attribute__((address_space(1))) void*)g,
        (__attribute__((address_space(3))) void*)l, 16, 0, 0);
}

__device__ __forceinline__ void pinreg(i32x4& v) { asm volatile("" : "+v"(v)); }
__device__ __forceinline__ void pini(int& v)     { asm volatile("" : "+v"(v)); }

__device__ __forceinline__ i32x16 zero16i() {
    i32x16 z;
    #pragma unroll
    for (int i = 0; i < 16; ++i) z[i] = 0;
    return z;
}

// exact KSEL-smallest scan over ints v[0..n), n >= KSEL; a[] gets them; returns the KSEL-th
__device__ __forceinline__ int topk_scan_i(const int* v, int n, int* a) {
    #pragma unroll
    for (int p = 0; p < KSEL; ++p) a[p] = v[p];
    int mx = a[0];
    #pragma unroll
    for (int p = 1; p < KSEL; ++p) mx = max(mx, a[p]);
    for (int i = KSEL; i < n; ++i) {
        const int x = v[i];
        if (x < mx) {
            bool done = false;
            #pragma unroll
            for (int p = 0; p < KSEL; ++p) {
                const bool rep = (!done) && (a[p] == mx);
                a[p] = rep ? x : a[p];
                done = done || rep;
            }
            mx = a[0];
            #pragma unroll
            for (int p = 1; p < KSEL; ++p) mx = max(mx, a[p]);
        }
    }
    return mx;
}

// ---- kernel 1: fp32 -> i8 quantize into 32-wide fragment-major layout + sqi = ||xi8||^2
//   byte(row,k) = (row>>5)*16384 + (k>>5)*1024 + ((k>>4)&1)*512 + (row&31)*16 + (k&15)
//   (lane-linear: one ds_read_b128 at base + lane*16 = one 32x32x32 A/B k-slice)
__global__ void prep_convert(const float* __restrict__ obs, char* __restrict__ obsb,
                             int* __restrict__ sqi) {
    const int wv = threadIdx.x >> 6, ln = threadIdx.x & 63;
    const int row = blockIdx.x * 4 + wv;
    const float4* s = (const float4*)(obs + (unsigned long)row * DIM + ln * 8);
    const float4 a = s[0], b = s[1];
    float xs[8] = {a.x, a.y, a.z, a.w, b.x, b.y, b.z, b.w};
    unsigned long u = 0ul;
    int ssum = 0;
    #pragma unroll
    for (int j = 0; j < 8; ++j) {
        const int q = __float2int_rn(fminf(fmaxf(xs[j] * QS, -127.f), 127.f));
        ssum += q * q;
        u |= ((unsigned long)((unsigned)q & 0xffu)) << (8 * j);
    }
    // lane ln owns k0 = ln*8: k>>5 = ln>>2, (k>>4)&1 = (ln>>1)&1, k&15 = (ln&1)*8
    *(unsigned long*)(obsb + (unsigned long)(row >> 5) * STRIPB + (ln >> 2) * 1024
                      + ((ln >> 1) & 1) * 512 + (row & 31) * 16 + (ln & 1) * 8) = u;
    #pragma unroll
    for (int off = 32; off; off >>= 1) ssum += __shfl_xor(ssum, off);
    if (ln == 0) sqi[row] = ssum;
}

// ---- shared staging macro: BN=64 tile = 2 strips = 32 KB, wave wv copies 8 KB lane-linear
#define STAGE(BUF, CITER) do {                                                  \
        const char* gs_ = obsb + (unsigned long)((C0 >> 5) + 2 * (CITER)) * STRIPB \
                          + wv * 8192 + ln * 16;                                \
        char* lb_ = &Braw[BUF][0] + wv * 8192;                                  \
        _Pragma("unroll")                                                       \
        for (int r_ = 0; r_ < 8; ++r_)                                          \
            gload_lds16(gs_ + r_ * 1024, lb_ + r_ * 1024);                      \
    } while (0)

// C/D mapping for mfma(b_colfrag, a_rowfrag): obs_row = lane&31 (+strip*32),
// obs_col = (r&3) + 8*(r>>2) + 4*(lane>>5) (+cg*32) [m74/m101, shape-determined]
#define COLIDX(CG, RQ) ((CG) * 32 + (RQ) * 8 + (ln >> 5) * 4)

// ---- kernel 2: threshold pass — per (row-tile, quarter): 11 smallest of 64
//   slot-minima over 1024 distinct cols (each an ACTUAL int distance) -> Tv
__global__ __launch_bounds__(256, 2) void thresh_pass(
    const char* __restrict__ obsb, const int* __restrict__ sqi,
    int* __restrict__ Tv)
{
    __shared__ __align__(16) char Braw[2][BN * 512];    // 64 KB double buffer

    const int tid = threadIdx.x;
    const int wv = tid >> 6, ln = tid & 63;
    const int q  = blockIdx.x >> 7;          // quarter-sample 0..3
    const int rt = blockIdx.x & 127;         // row tile 0..127
    const int R0 = rt * BMT;
    const int C0 = q * TCH;                  // sample = first 1024 cols of chunk q
    const int wrow0 = R0 + wv * 32;          // one 32-row strip per wave

    // A fragments: 1 strip x 16 k-chunks, pinned
    i32x4 afrag[16];
    int sqr;
    {
        const unsigned long sbase = (unsigned long)((R0 >> 5) + wv) * STRIPB;
        #pragma unroll
        for (int t = 0; t < 16; ++t) {
            afrag[t] = *(const i32x4*)(obsb + sbase + t * 1024 + ln * 16);
            pinreg(afrag[t]);
        }
        sqr = sqi[wrow0 + (ln & 31)];
        pini(sqr);
    }

    int segmin[2][16];
    #pragma unroll
    for (int cg = 0; cg < 2; ++cg)
        #pragma unroll
        for (int r = 0; r < 16; ++r) segmin[cg][r] = 0x7FFFFFFF;

    STAGE(0, 0);
    __syncthreads();
    #pragma unroll 2
    for (int it = 0; it < TITERS; ++it) {
        const int cur = it & 1;
        if (it + 1 < TITERS) STAGE(cur ^ 1, it + 1);
        const char* bp = &Braw[cur][0];
        i32x16 acc[2] = {zero16i(), zero16i()};
        #pragma unroll
        for (int cg = 0; cg < 2; ++cg)
            #pragma unroll
            for (int t = 0; t < 16; ++t) {
                const i32x4 b = *(const i32x4*)(bp + cg * STRIPB + t * 1024 + ln * 16);
                acc[cg] = __builtin_amdgcn_mfma_i32_32x32x32_i8(b, afrag[t], acc[cg], 0, 0, 0);
            }
        i32x4 sqv[2][4];
        #pragma unroll
        for (int cg = 0; cg < 2; ++cg)
            #pragma unroll
            for (int rq = 0; rq < 4; ++rq)
                sqv[cg][rq] = *(const i32x4*)(sqi + C0 + it * BN + COLIDX(cg, rq));
        #pragma unroll
        for (int cg = 0; cg < 2; ++cg)
            #pragma unroll
            for (int r = 0; r < 16; ++r) {
                const int v = sqr + sqv[cg][r >> 2][r & 3] - 2 * acc[cg][r];
                segmin[cg][r] = min(segmin[cg][r], v);
            }
        __syncthreads();
    }

    // gather 64 slot-minima per row (2 lanes x 32 slots), stride 65 -> 11 smallest
    int* mins = (int*)&Braw[0][0];               // [BMT][65] = 33 KB
    #pragma unroll
    for (int cg = 0; cg < 2; ++cg)
        #pragma unroll
        for (int r = 0; r < 16; ++r)
            mins[(wv * 32 + (ln & 31)) * 65 + (ln >> 5) * 32 + cg * 16 + r] = segmin[cg][r];
    __syncthreads();
    if (tid < BMT) {
        int a[KSEL];
        topk_scan_i(mins + tid * 65, 64, a);
        #pragma unroll
        for (int p = 0; p < KSEL; ++p)
            Tv[(unsigned long)(R0 + tid) * (4 * KSEL) + q * KSEL + p] = a[p];
    }
}

// ---- kernel 3: T[row] = 11th smallest of the 44 quarter values (provable upper bound)
__global__ void tmerge(const int* __restrict__ Tv, int* __restrict__ T) {
    const int row = blockIdx.x * 256 + threadIdx.x;
    int a[KSEL];
    T[row] = topk_scan_i(Tv + (unsigned long)row * (4 * KSEL), 4 * KSEL, a);
}

// ---- kernel 4: main pass — 2 row-strips x 2 col-strips of 32 (64x64/wave), 32x32x32 i8
__global__ __launch_bounds__(256, 2) void knn_main(
    const char* __restrict__ obsb, const int* __restrict__ sqi,
    const int* __restrict__ T, int* __restrict__ cnt,
    int* __restrict__ vals)
{
    __shared__ __align__(16) char Braw[2][BN * 512];    // 64 KB double buffer
    __shared__ unsigned lcnt[BMM];

    const int tid = threadIdx.x;
    const int wv = tid >> 6, ln = tid & 63;
    const int sp = blockIdx.x >> 6;          // split 0..7
    const int rt = blockIdx.x & 63;          // row tile 0..63
    const int R0 = rt * BMM;
    const int C0 = sp * CPS;
    const int wrow0 = R0 + wv * 64;

    lcnt[tid] = 0u;

    // A fragments: 2 strips x 16 k-chunks (128 VGPRs), pinned
    i32x4 afrag[2][16];
    int sqr[2];
    #pragma unroll
    for (int s = 0; s < 2; ++s) {
        const unsigned long sbase = (unsigned long)((R0 >> 5) + wv * 2 + s) * STRIPB;
        #pragma unroll
        for (int t = 0; t < 16; ++t) {
            afrag[s][t] = *(const i32x4*)(obsb + sbase + t * 1024 + ln * 16);
            pinreg(afrag[s][t]);
        }
        sqr[s] = sqi[wrow0 + s * 32 + (ln & 31)];
        pini(sqr[s]);
    }

    unsigned lrow[2]; int tval[2]; int* vbase[2];
    #pragma unroll
    for (int s = 0; s < 2; ++s) {
        const int row = wrow0 + s * 32 + (ln & 31);
        lrow[s]  = wv * 64 + s * 32 + (ln & 31);
        tval[s]  = T[row];                   // exact int gate
        pini(tval[s]);
        vbase[s] = vals + ((unsigned long)row * NSPLIT + sp) * CAP;
    }

    STAGE(0, 0);
    __syncthreads();
    #pragma unroll 2
    for (int it = 0; it < MITERS; ++it) {
        const int cur = it & 1;
        if (it + 1 < MITERS) STAGE(cur ^ 1, it + 1);
        // GEMM: 32 ds_read_b128, 64 MFMA 32x32x32 i8 (each b reused 2x, 2x MACs each)
        const char* bp = &Braw[cur][0];
        i32x16 acc[2][2] = {{zero16i(), zero16i()}, {zero16i(), zero16i()}};
        #pragma unroll
        for (int cg = 0; cg < 2; ++cg)
            #pragma unroll
            for (int t = 0; t < 16; ++t) {
                const i32x4 b = *(const i32x4*)(bp + cg * STRIPB + t * 1024 + ln * 16);
                acc[0][cg] = __builtin_amdgcn_mfma_i32_32x32x32_i8(b, afrag[0][t], acc[0][cg], 0, 0, 0);
                acc[1][cg] = __builtin_amdgcn_mfma_i32_32x32x32_i8(b, afrag[1][t], acc[1][cg], 0, 0, 0);
            }
        i32x4 sqv[2][4];
        #pragma unroll
        for (int cg = 0; cg < 2; ++cg)
            #pragma unroll
            for (int rq = 0; rq < 4; ++rq)
                sqv[cg][rq] = *(const i32x4*)(sqi + C0 + it * BN + COLIDX(cg, rq));
        // rare predicated append (exact int gate)
        #pragma unroll
        for (int s = 0; s < 2; ++s)
            #pragma unroll
            for (int cg = 0; cg < 2; ++cg)
                #pragma unroll
                for (int r = 0; r < 16; ++r) {
                    const int v_ = sqr[s] + sqv[cg][r >> 2][r & 3] - 2 * acc[s][cg][r];
                    if (v_ <= tval[s]) {
                        const unsigned i_ = atomicAdd(&lcnt[lrow[s]], 1u);
                        if (i_ < CAP) vbase[s][i_] = v_;
                    }
                }
        __syncthreads();
    }

    {
        const unsigned c = lcnt[tid];
        cnt[(unsigned long)(R0 + tid) * NSPLIT + sp] = (int)(c < CAP ? c : CAP);
    }
}

// ---- kernel 5: per row, exact top-11 of appended int candidates -> output
__global__ void merge_out(const int* __restrict__ cnt, const int* __restrict__ vals,
                          float* __restrict__ out) {
    const int row = blockIdx.x * 256 + threadIdx.x;
    int arr[KSEL];
    #pragma unroll
    for (int p = 0; p < KSEL; ++p) arr[p] = 0x7FFFFFFF;
    int mx = 0x7FFFFFFF;
    for (int q = 0; q < NSPLIT; ++q) {
        const int n = min(cnt[(unsigned long)row * NSPLIT + q], CAP);
        const int* base = vals + ((unsigned long)row * NSPLIT + q) * CAP;
        for (int i = 0; i < n; ++i) {
            const int x = base[i];
            if (x < mx) {
                bool done = false;
                #pragma unroll
                for (int p = 0; p < KSEL; ++p) {
                    const bool rep = (!done) && (arr[p] == mx);
                    arr[p] = rep ? x : arr[p];
                    done = done || rep;
                }
                mx = arr[0];
                #pragma unroll
                for (int p = 1; p < KSEL; ++p) mx = max(mx, arr[p]);
            }
        }
    }
    int mn = arr[0];
    #pragma unroll
    for (int p = 1; p < KSEL; ++p) mn = min(mn, arr[p]);
    float ssum = 0.f;
    #pragma unroll
    for (int p = 0; p < KSEL; ++p) ssum += sqrtf((float)max(arr[p], 0));
    const float smn = sqrtf((float)max(mn, 0));
    out[row] = log1pf((ssum - smn) * (0.1f / QS));   // r = sqrt(d2i)/QS; mean of 10
}

extern "C" void kernel_launch(void* const* d_in, const int* in_sizes, int n_in,
                              void* d_out, int out_size, void* d_ws, size_t ws_size,
                              hipStream_t stream) {
    const float* obs = (const float*)d_in[0];
    float* out = (float*)d_out;
    char* ws = (char*)d_ws;

    char* obsb = ws;                                         // 8 MB fragment-major i8
    int*  sqi  = (int*)(ws + (size_t)NPTS * 512);            // 64 KB
    int*  T    = sqi + NPTS;                                 // 64 KB
    int*  cnt  = T + NPTS;                                   // 512 KB
    int*  vals = cnt + NPTS * NSPLIT;                        // 12.6 MB (8 x CAP=24)
    int*  Tv   = vals;   // aliased: Tv (2.75 MB) consumed by tmerge BEFORE
                         // knn_main writes vals (stream-ordered, no overlap)

    prep_convert<<<NPTS / 4, 256, 0, stream>>>(obs, obsb, sqi);
    thresh_pass<<<128 * 4, 256, 0, stream>>>(obsb, sqi, Tv);
    tmerge<<<NPTS / 256, 256, 0, stream>>>(Tv, T);
    knn_main<<<64 * NSPLIT, 256, 0, stream>>>(obsb, sqi, T, cnt, vals);
    merge_out<<<NPTS / 256, 256, 0, stream>>>(cnt, vals, out);
}